// Round 1
// baseline (5819.774 us; speedup 1.0000x reference)
//
#include <hip/hip_runtime.h>
#include <hip/hip_bf16.h>
#include <cstddef>
#include <cstdint>

#define BB 64
#define TT 4096
#define HD 64

__device__ __forceinline__ float sigf(float v) {
    return 1.0f / (1.0f + __expf(-v));
}
__device__ __forceinline__ float tanhf_fast(float v) {
    // 1 - 2/(e^{2v}+1); saturates correctly for |v| large (inf -> 1, 0 -> -1)
    return 1.0f - 2.0f / (__expf(2.0f * v) + 1.0f);
}

// ---------------------------------------------------------------------------
// Kernel 1: per-(batch, feature) mean / rstd over T (instance norm stats)
// stats layout: [0 .. B*64)   = mu
//               [B*64 .. 2*B*64) = rsqrt(var + eps)
// ---------------------------------------------------------------------------
__global__ __launch_bounds__(1024) void stats_kernel(const float* __restrict__ x,
                                                     float* __restrict__ stats) {
    const int b = blockIdx.x;
    const int f = threadIdx.x & 63;
    const int grp = threadIdx.x >> 6;  // 0..15
    const float* xb = x + (size_t)b * TT * HD;
    float s = 0.f, s2 = 0.f;
    for (int t = grp; t < TT; t += 16) {
        float v = xb[t * HD + f];
        s += v;
        s2 = fmaf(v, v, s2);
    }
    __shared__ float ls[16][64];
    __shared__ float ls2[16][64];
    ls[grp][f] = s;
    ls2[grp][f] = s2;
    __syncthreads();
    if (threadIdx.x < 64) {
        float ss = 0.f, ss2 = 0.f;
#pragma unroll
        for (int i = 0; i < 16; ++i) {
            ss += ls[i][f];
            ss2 += ls2[i][f];
        }
        float mu = ss * (1.0f / TT);
        float var = ss2 * (1.0f / TT) - mu * mu;  // biased var, like torch/jnp.var
        stats[b * HD + f] = mu;
        stats[BB * HD + b * HD + f] = rsqrtf(var + 1e-5f);
    }
}

// ---------------------------------------------------------------------------
// Kernel 2: fused (norm-apply + LSTM0 + LSTM1 + FC + residual), one block per
// batch element, persistent over all T steps.
//
// 512 threads: thread (g = tid>>1, half = tid&1) owns half of gate row g for
// both layers; weights live in VGPRs (4 * 32 = 128 floats / thread).
// h0/h1 live in LDS (broadcast reads); c0/c1 live in lane registers of the
// first wave. Gate activations are applied by the gate threads (parallel)
// so the 64-lane update phase only does the c/h combine + one tanh.
// FC + residual is computed by all 512 threads (8 lanes per output) and
// stored fire-and-forget.
// ---------------------------------------------------------------------------
__global__ __launch_bounds__(512) void rnn_fused(
    const float* __restrict__ x,
    const float* __restrict__ Wih0, const float* __restrict__ Whh0,
    const float* __restrict__ bih0, const float* __restrict__ bhh0,
    const float* __restrict__ Wih1, const float* __restrict__ Whh1,
    const float* __restrict__ bih1, const float* __restrict__ bhh1,
    const float* __restrict__ Wfc, const float* __restrict__ bfc,
    const float* __restrict__ stats,
    float* __restrict__ out) {
    const int b = blockIdx.x;
    const int tid = threadIdx.x;
    const int g = tid >> 1;       // gate row 0..255
    const int half = tid & 1;     // which 32-wide half of the dot
    const int koff = half << 5;   // 0 or 32
    const int gtype = g >> 6;     // 0:i 1:f 2:g 3:o  (uniform per wave)

    // ---- per-thread weight registers (one-time global loads) ----
    float wih0[32], whh0[32], wih1[32], whh1[32];
#pragma unroll
    for (int k = 0; k < 32; ++k) {
        wih0[k] = Wih0[g * 64 + koff + k];
        whh0[k] = Whh0[g * 64 + koff + k];
        wih1[k] = Wih1[g * 64 + koff + k];
        whh1[k] = Whh1[g * 64 + koff + k];
    }
    const float B0 = bih0[g] + bhh0[g];
    const float B1 = bih1[g] + bhh1[g];

    // FC assignment: output column fj, 8-wide slice fpart (shuffle-reduced)
    const int fj = tid >> 3;
    const int fpart = tid & 7;
    float wfc[8];
#pragma unroll
    for (int k = 0; k < 8; ++k) wfc[k] = Wfc[fj * 64 + fpart * 8 + k];
    const float bfc_r = bfc[fj];

    __shared__ float h0_lds[64];
    __shared__ float h1_lds[64];
    __shared__ float gates_lds[256];
    __shared__ float xn_lds[2][64];    // normalized input, double buffered
    __shared__ float xraw_lds[2][64];  // raw input for the residual
    __shared__ float mu_s[64];
    __shared__ float rs_s[64];

    const float* xrow = x + (size_t)b * TT * HD;
    float* orow = out + (size_t)b * TT * HD;

    if (tid < 64) {
        float mu = stats[b * HD + tid];
        float rs = stats[BB * HD + b * HD + tid];
        mu_s[tid] = mu;
        rs_s[tid] = rs;
        h0_lds[tid] = 0.f;
        h1_lds[tid] = 0.f;
        float xv = xrow[tid];  // t = 0
        xraw_lds[0][tid] = xv;
        xn_lds[0][tid] = (xv - mu) * rs;
    }
    float c0 = 0.f, c1 = 0.f;
    __syncthreads();

    for (int t = 0; t < TT; ++t) {
        const int par = t & 1;

        // prefetch next timestep's input (off critical path)
        float xnext = 0.f;
        if (tid < 64 && t + 1 < TT) xnext = xrow[(t + 1) * HD + tid];

        // ---- layer 0 gates: Wih0 * xn_t + Whh0 * h0 ----
        float acc = 0.f;
#pragma unroll
        for (int k = 0; k < 32; ++k) acc = fmaf(whh0[k], h0_lds[koff + k], acc);
#pragma unroll
        for (int k = 0; k < 32; ++k) acc = fmaf(wih0[k], xn_lds[par][koff + k], acc);
        acc += __shfl_xor(acc, 1);
        {
            float gate = acc + B0;
            float av = (gtype == 2) ? tanhf_fast(gate) : sigf(gate);
            if (half == 0) gates_lds[g] = av;
        }
        __syncthreads();  // bar 1

        // ---- layer 0 state update (wave 0) ----
        if (tid < 64) {
            float ai = gates_lds[tid];
            float af = gates_lds[64 + tid];
            float ag = gates_lds[128 + tid];
            float ao = gates_lds[192 + tid];
            c0 = fmaf(af, c0, ai * ag);
            h0_lds[tid] = ao * tanhf_fast(c0);
        }
        __syncthreads();  // bar 2

        // ---- layer 1 gates: Wih1 * h0_t + Whh1 * h1 ----
        acc = 0.f;
#pragma unroll
        for (int k = 0; k < 32; ++k) acc = fmaf(wih1[k], h0_lds[koff + k], acc);
#pragma unroll
        for (int k = 0; k < 32; ++k) acc = fmaf(whh1[k], h1_lds[koff + k], acc);
        acc += __shfl_xor(acc, 1);
        {
            float gate = acc + B1;
            float av = (gtype == 2) ? tanhf_fast(gate) : sigf(gate);
            if (half == 0) gates_lds[g] = av;
        }
        // stage next timestep's normalized input (double buffer, other parity)
        if (tid < 64 && t + 1 < TT) {
            xraw_lds[par ^ 1][tid] = xnext;
            xn_lds[par ^ 1][tid] = (xnext - mu_s[tid]) * rs_s[tid];
        }
        __syncthreads();  // bar 3

        // ---- layer 1 state update (wave 0) ----
        if (tid < 64) {
            float ai = gates_lds[tid];
            float af = gates_lds[64 + tid];
            float ag = gates_lds[128 + tid];
            float ao = gates_lds[192 + tid];
            c1 = fmaf(af, c1, ai * ag);
            h1_lds[tid] = ao * tanhf_fast(c1);
        }
        __syncthreads();  // bar 4

        // ---- FC + bias + residual (off critical path, fire and forget) ----
        float f = 0.f;
#pragma unroll
        for (int k = 0; k < 8; ++k) f = fmaf(wfc[k], h1_lds[fpart * 8 + k], f);
        f += __shfl_xor(f, 1);
        f += __shfl_xor(f, 2);
        f += __shfl_xor(f, 4);
        if (fpart == 0) orow[t * HD + fj] = f + bfc_r + xraw_lds[par][fj];
    }
}

// ---------------------------------------------------------------------------
extern "C" void kernel_launch(void* const* d_in, const int* in_sizes, int n_in,
                              void* d_out, int out_size, void* d_ws, size_t ws_size,
                              hipStream_t stream) {
    const float* x    = (const float*)d_in[0];
    const float* Wih0 = (const float*)d_in[1];
    const float* Whh0 = (const float*)d_in[2];
    const float* bih0 = (const float*)d_in[3];
    const float* bhh0 = (const float*)d_in[4];
    const float* Wih1 = (const float*)d_in[5];
    const float* Whh1 = (const float*)d_in[6];
    const float* bih1 = (const float*)d_in[7];
    const float* bhh1 = (const float*)d_in[8];
    const float* Wfc  = (const float*)d_in[9];
    const float* bfc  = (const float*)d_in[10];

    float* stats = (float*)d_ws;  // 2 * 64 * 64 floats = 32 KiB
    float* out = (float*)d_out;

    stats_kernel<<<64, 1024, 0, stream>>>(x, stats);
    rnn_fused<<<64, 512, 0, stream>>>(x, Wih0, Whh0, bih0, bhh0,
                                      Wih1, Whh1, bih1, bhh1,
                                      Wfc, bfc, stats, out);
}

// Round 2
// 3933.797 us; speedup vs baseline: 1.4794x; 1.4794x over previous
//
#include <hip/hip_runtime.h>
#include <hip/hip_bf16.h>
#include <cstddef>
#include <cstdint>

#define BB 64
#define TT 4096
#define HD 64
#define CH 16

__device__ __forceinline__ float sigf(float v) {
    return 1.0f / (1.0f + __expf(-v));
}
__device__ __forceinline__ float tanhf_fast(float v) {
    return 1.0f - 2.0f / (__expf(2.0f * v) + 1.0f);
}

// ---------------------------------------------------------------------------
// Stats pass 1: 256 blocks = (batch b = blk>>2, T-segment seg = blk&3).
// part layout: [0..256*64) partial sums, [256*64..2*256*64) partial sumsq.
// ---------------------------------------------------------------------------
__global__ __launch_bounds__(256) void stats_part(const float* __restrict__ x,
                                                  float* __restrict__ part) {
    const int b = blockIdx.x >> 2, seg = blockIdx.x & 3;
    const int f = threadIdx.x & 63, grp = threadIdx.x >> 6;  // grp 0..3
    const float* xb = x + (size_t)b * TT * HD + (size_t)seg * (TT / 4) * HD;
    float s = 0.f, s2 = 0.f;
    for (int t = grp; t < TT / 4; t += 4) {
        float v = xb[t * HD + f];
        s += v;
        s2 = fmaf(v, v, s2);
    }
    __shared__ float ls[4][64];
    __shared__ float ls2[4][64];
    ls[grp][f] = s;
    ls2[grp][f] = s2;
    __syncthreads();
    if (threadIdx.x < 64) {
        float ss = 0.f, ss2 = 0.f;
#pragma unroll
        for (int i = 0; i < 4; ++i) { ss += ls[i][f]; ss2 += ls2[i][f]; }
        part[blockIdx.x * HD + f] = ss;
        part[256 * HD + blockIdx.x * HD + f] = ss2;
    }
}

// Stats pass 2: mu and rsqrt(var+eps). stats: [0..B*64) mu, [B*64..) rstd.
__global__ __launch_bounds__(64) void stats_fin(const float* __restrict__ part,
                                                float* __restrict__ stats) {
    const int b = blockIdx.x, f = threadIdx.x;
    float s = 0.f, s2 = 0.f;
#pragma unroll
    for (int seg = 0; seg < 4; ++seg) {
        s += part[(b * 4 + seg) * HD + f];
        s2 += part[256 * HD + (b * 4 + seg) * HD + f];
    }
    float mu = s * (1.0f / TT);
    float var = s2 * (1.0f / TT) - mu * mu;
    stats[b * HD + f] = mu;
    stats[BB * HD + b * HD + f] = rsqrtf(var + 1e-5f);
}

// ---------------------------------------------------------------------------
// Persistent recurrent kernel: 64 blocks x 512 threads, 2 barriers/step.
// Pipeline skew: layer 0 runs one step ahead of layer 1.
//   loop entry invariants: h0_lds=h0(t), h1_lds=h1(t-1), c0=c0(t), c1=c1(t-1)
//   phase1 (all): gates1(t) = act(Wih1 h0(t) + Whh1 h1(t-1) + B1)
//                 gates0(t+1) = act(Whh0 h0(t) + Wih0 xn(t+1) + B0)
//   phase2 (wave0): c1,h1(t) update;  c0,h0(t+1) update
// x staged per 16-step chunk (load at tc==0, LDS-write at tc==8); h1 written
// to h1hist and flushed to global once per chunk. FC is a separate kernel.
// ---------------------------------------------------------------------------
__global__ __launch_bounds__(512, 2) void rnn_fused(
    const float* __restrict__ x,
    const float* __restrict__ Wih0, const float* __restrict__ Whh0,
    const float* __restrict__ bih0, const float* __restrict__ bhh0,
    const float* __restrict__ Wih1, const float* __restrict__ Whh1,
    const float* __restrict__ bih1, const float* __restrict__ bhh1,
    const float* __restrict__ stats,
    float* __restrict__ h1out) {
    const int b = blockIdx.x;
    const int tid = threadIdx.x;
    const int g = tid >> 1;      // gate row 0..255
    const int half = tid & 1;    // 32-wide half of each 64-dot
    const int koff = half << 5;
    const int gtype = g >> 6;    // 0:i 1:f 2:g 3:o

    // ---- weights in VGPRs: 32 float4 = 128 regs (LB(512,2) gives 256 budget)
    float4 wih0[8], whh0[8], wih1[8], whh1[8];
    {
        const float4* p0 = (const float4*)(Wih0 + g * HD + koff);
        const float4* p1 = (const float4*)(Whh0 + g * HD + koff);
        const float4* p2 = (const float4*)(Wih1 + g * HD + koff);
        const float4* p3 = (const float4*)(Whh1 + g * HD + koff);
#pragma unroll
        for (int r = 0; r < 8; ++r) {
            wih0[r] = p0[r];
            whh0[r] = p1[r];
            wih1[r] = p2[r];
            whh1[r] = p3[r];
        }
    }
    const float B0 = bih0[g] + bhh0[g];
    const float B1 = bih1[g] + bhh1[g];

    // normalization constants for this thread's 2 staging features
    const int f0 = (2 * tid) & 63;
    const float mu0 = stats[b * HD + f0];
    const float mu1 = stats[b * HD + f0 + 1];
    const float rs0 = stats[BB * HD + b * HD + f0];
    const float rs1 = stats[BB * HD + b * HD + f0 + 1];

    __shared__ __align__(16) float h0_lds[HD];
    __shared__ __align__(16) float h1_lds[HD];
    __shared__ __align__(16) float gates_lds[512];   // [0..256) L1(t), [256..512) L0(t+1)
    __shared__ __align__(16) float xn[2][CH][HD];    // normalized x, chunk double buffer
    __shared__ __align__(16) float h1hist[CH][HD];   // h1 history for chunked flush

    const float* xrow = x + (size_t)b * TT * HD;
    float* hrow = h1out + (size_t)b * TT * HD;

    float c0 = 0.f, c1 = 0.f;

    // ---- prologue: stage chunk 0, zero states ----
    {
        float2 v = ((const float2*)xrow)[tid];  // steps 0..15
        ((float2*)&xn[0][0][0])[tid] = make_float2((v.x - mu0) * rs0, (v.y - mu1) * rs1);
        if (tid < HD) { h0_lds[tid] = 0.f; h1_lds[tid] = 0.f; }
    }
    __syncthreads();
    // prologue: gates0(0) with h0(-1)=0
    {
        float q0 = 0.f, q1 = 0.f, q2 = 0.f, q3 = 0.f;
        const float4* xp = (const float4*)&xn[0][0][koff];
#pragma unroll
        for (int r = 0; r < 8; ++r) {
            float4 xq = xp[r];
            q0 = fmaf(wih0[r].x, xq.x, q0);
            q1 = fmaf(wih0[r].y, xq.y, q1);
            q2 = fmaf(wih0[r].z, xq.z, q2);
            q3 = fmaf(wih0[r].w, xq.w, q3);
        }
        float gp = (q0 + q1) + (q2 + q3);
        gp += __shfl_xor(gp, 1);
        gp += B0;
        float av = (gtype == 2) ? tanhf_fast(gp) : sigf(gp);
        if (half == 0) gates_lds[256 + g] = av;
    }
    __syncthreads();
    if (tid < HD) {
        float i0 = gates_lds[256 + tid], ff0 = gates_lds[320 + tid];
        float gg0 = gates_lds[384 + tid], o0 = gates_lds[448 + tid];
        c0 = i0 * gg0;  // c(-1)=0
        h0_lds[tid] = o0 * tanhf_fast(c0);
        (void)ff0;
    }
    __syncthreads();

    float2 xs = make_float2(0.f, 0.f);
    for (int t = 0; t < TT; ++t) {
        const int tc = t & (CH - 1);

        // issue next chunk's global load (consumed CH-1 steps later)
        if (tc == 0 && t + CH < TT) {
            xs = ((const float2*)(xrow + (size_t)(t + CH) * HD))[tid];
        }
        // normalize + LDS-write the staged chunk mid-chunk
        if (tc == (CH / 2) && t + CH / 2 < TT) {
            const int par = ((t >> 4) + 1) & 1;
            ((float2*)&xn[par][0][0])[tid] =
                make_float2((xs.x - mu0) * rs0, (xs.y - mu1) * rs1);
        }

        // ---- phase 1: both gate sets ----
        const int s1 = t + 1;
        const float4* h0p = (const float4*)&h0_lds[koff];
        const float4* h1p = (const float4*)&h1_lds[koff];
        const float4* xp = (const float4*)&xn[(s1 >> 4) & 1][s1 & (CH - 1)][koff];
        float a0 = 0.f, a1 = 0.f, a2 = 0.f, a3 = 0.f;  // layer1 gate acc
        float q0 = 0.f, q1 = 0.f, q2 = 0.f, q3 = 0.f;  // layer0(t+1) gate acc
#pragma unroll
        for (int r = 0; r < 8; ++r) {
            float4 h0q = h0p[r];
            float4 h1q = h1p[r];
            float4 xq = xp[r];
            a0 = fmaf(wih1[r].x, h0q.x, a0);
            a1 = fmaf(wih1[r].y, h0q.y, a1);
            a2 = fmaf(wih1[r].z, h0q.z, a2);
            a3 = fmaf(wih1[r].w, h0q.w, a3);
            a0 = fmaf(whh1[r].x, h1q.x, a0);
            a1 = fmaf(whh1[r].y, h1q.y, a1);
            a2 = fmaf(whh1[r].z, h1q.z, a2);
            a3 = fmaf(whh1[r].w, h1q.w, a3);
            q0 = fmaf(whh0[r].x, h0q.x, q0);
            q1 = fmaf(whh0[r].y, h0q.y, q1);
            q2 = fmaf(whh0[r].z, h0q.z, q2);
            q3 = fmaf(whh0[r].w, h0q.w, q3);
            q0 = fmaf(wih0[r].x, xq.x, q0);
            q1 = fmaf(wih0[r].y, xq.y, q1);
            q2 = fmaf(wih0[r].z, xq.z, q2);
            q3 = fmaf(wih0[r].w, xq.w, q3);
        }
        float g1 = (a0 + a1) + (a2 + a3);
        float g0v = (q0 + q1) + (q2 + q3);
        g1 += __shfl_xor(g1, 1);
        g0v += __shfl_xor(g0v, 1);
        g1 += B1;
        g0v += B0;
        float av1 = (gtype == 2) ? tanhf_fast(g1) : sigf(g1);
        float av0 = (gtype == 2) ? tanhf_fast(g0v) : sigf(g0v);
        if (half == 0) {
            gates_lds[g] = av1;
            gates_lds[256 + g] = av0;
        }
        __syncthreads();  // BAR A

        // ---- phase 2: both cell updates (wave 0) ----
        if (tid < HD) {
            float i1 = gates_lds[tid], f1 = gates_lds[64 + tid];
            float gg1 = gates_lds[128 + tid], o1 = gates_lds[192 + tid];
            float i0 = gates_lds[256 + tid], ff0 = gates_lds[320 + tid];
            float gg0 = gates_lds[384 + tid], o0 = gates_lds[448 + tid];
            c1 = fmaf(f1, c1, i1 * gg1);
            float hv1 = o1 * tanhf_fast(c1);
            h1_lds[tid] = hv1;
            h1hist[tc][tid] = hv1;
            c0 = fmaf(ff0, c0, i0 * gg0);
            h0_lds[tid] = o0 * tanhf_fast(c0);
        }
        __syncthreads();  // BAR B

        // ---- flush h1 chunk to global (coalesced, once per CH steps) ----
        if (tc == CH - 1) {
            float2 hv = ((const float2*)&h1hist[0][0])[tid];
            ((float2*)(hrow + (size_t)(t - (CH - 1)) * HD))[tid] = hv;
        }
    }
}

// ---------------------------------------------------------------------------
// FC + bias + residual, in place on d_out (hout holds h1, rewritten as out).
// One thread per row-of-64; Wfc staged in LDS, read wave-uniform (broadcast);
// h1 row held in registers, so in-place is hazard-free per thread.
// ---------------------------------------------------------------------------
__global__ __launch_bounds__(256) void fc_res(float* __restrict__ hout,
                                              const float* __restrict__ x,
                                              const float* __restrict__ Wfc,
                                              const float* __restrict__ bfc) {
    __shared__ __align__(16) float wfc_lds[HD * HD];
    __shared__ float bfc_lds[HD];
    const int tid = threadIdx.x;
#pragma unroll
    for (int i = 0; i < 4; ++i)
        ((float4*)wfc_lds)[tid + 256 * i] = ((const float4*)Wfc)[tid + 256 * i];
    if (tid < HD) bfc_lds[tid] = bfc[tid];

    const size_t row = (size_t)blockIdx.x * 256 + tid;
    float hr[HD];
    {
        const float4* hp = (const float4*)(hout + row * HD);
#pragma unroll
        for (int i = 0; i < 16; ++i) {
            float4 v = hp[i];
            hr[4 * i] = v.x; hr[4 * i + 1] = v.y;
            hr[4 * i + 2] = v.z; hr[4 * i + 3] = v.w;
        }
    }
    __syncthreads();

    const float4* xp = (const float4*)(x + row * HD);
    float4* op = (float4*)(hout + row * HD);
    for (int j4 = 0; j4 < 16; ++j4) {
        float s0 = 0.f, s1 = 0.f, s2 = 0.f, s3 = 0.f;
        const float* w0 = &wfc_lds[(4 * j4 + 0) * HD];
        const float* w1 = &wfc_lds[(4 * j4 + 1) * HD];
        const float* w2 = &wfc_lds[(4 * j4 + 2) * HD];
        const float* w3 = &wfc_lds[(4 * j4 + 3) * HD];
#pragma unroll
        for (int k = 0; k < HD; ++k) {
            s0 = fmaf(w0[k], hr[k], s0);
            s1 = fmaf(w1[k], hr[k], s1);
            s2 = fmaf(w2[k], hr[k], s2);
            s3 = fmaf(w3[k], hr[k], s3);
        }
        float4 xv = xp[j4];
        float4 o;
        o.x = s0 + bfc_lds[4 * j4 + 0] + xv.x;
        o.y = s1 + bfc_lds[4 * j4 + 1] + xv.y;
        o.z = s2 + bfc_lds[4 * j4 + 2] + xv.z;
        o.w = s3 + bfc_lds[4 * j4 + 3] + xv.w;
        op[j4] = o;
    }
}

// ---------------------------------------------------------------------------
extern "C" void kernel_launch(void* const* d_in, const int* in_sizes, int n_in,
                              void* d_out, int out_size, void* d_ws, size_t ws_size,
                              hipStream_t stream) {
    const float* x    = (const float*)d_in[0];
    const float* Wih0 = (const float*)d_in[1];
    const float* Whh0 = (const float*)d_in[2];
    const float* bih0 = (const float*)d_in[3];
    const float* bhh0 = (const float*)d_in[4];
    const float* Wih1 = (const float*)d_in[5];
    const float* Whh1 = (const float*)d_in[6];
    const float* bih1 = (const float*)d_in[7];
    const float* bhh1 = (const float*)d_in[8];
    const float* Wfc  = (const float*)d_in[9];
    const float* bfc  = (const float*)d_in[10];

    float* part  = (float*)d_ws;                 // 2*256*64 floats = 128 KiB
    float* stats = part + 2 * 256 * HD;          // 2*64*64 floats  =  32 KiB
    float* out   = (float*)d_out;

    stats_part<<<256, 256, 0, stream>>>(x, part);
    stats_fin<<<64, 64, 0, stream>>>(part, stats);
    rnn_fused<<<64, 512, 0, stream>>>(x, Wih0, Whh0, bih0, bhh0,
                                      Wih1, Whh1, bih1, bhh1, stats, out);
    fc_res<<<1024, 256, 0, stream>>>(out, x, Wfc, bfc);
}

// Round 3
// 3553.947 us; speedup vs baseline: 1.6376x; 1.1069x over previous
//
#include <hip/hip_runtime.h>
#include <cstddef>
#include <cstdint>

#define BB 64
#define TT 4096
#define HD 64
#define CH 32

typedef float v2f __attribute__((ext_vector_type(2)));

__device__ __forceinline__ float sigf(float v) {
    return 1.0f / (1.0f + __expf(-v));
}
__device__ __forceinline__ float tanhf_fast(float v) {
    return 1.0f - 2.0f / (__expf(2.0f * v) + 1.0f);
}

// ---------------------------------------------------------------------------
// Stats pass 1: 256 blocks = (batch b = blk>>2, T-segment seg = blk&3).
// ---------------------------------------------------------------------------
__global__ __launch_bounds__(256) void stats_part(const float* __restrict__ x,
                                                  float* __restrict__ part) {
    const int b = blockIdx.x >> 2, seg = blockIdx.x & 3;
    const int f = threadIdx.x & 63, grp = threadIdx.x >> 6;  // grp 0..3
    const float* xb = x + (size_t)b * TT * HD + (size_t)seg * (TT / 4) * HD;
    float s = 0.f, s2 = 0.f;
    for (int t = grp; t < TT / 4; t += 4) {
        float v = xb[t * HD + f];
        s += v;
        s2 = fmaf(v, v, s2);
    }
    __shared__ float ls[4][64];
    __shared__ float ls2[4][64];
    ls[grp][f] = s;
    ls2[grp][f] = s2;
    __syncthreads();
    if (threadIdx.x < 64) {
        float ss = 0.f, ss2 = 0.f;
#pragma unroll
        for (int i = 0; i < 4; ++i) { ss += ls[i][f]; ss2 += ls2[i][f]; }
        part[blockIdx.x * HD + f] = ss;
        part[256 * HD + blockIdx.x * HD + f] = ss2;
    }
}

__global__ __launch_bounds__(64) void stats_fin(const float* __restrict__ part,
                                                float* __restrict__ stats) {
    const int b = blockIdx.x, f = threadIdx.x;
    float s = 0.f, s2 = 0.f;
#pragma unroll
    for (int seg = 0; seg < 4; ++seg) {
        s += part[(b * 4 + seg) * HD + f];
        s2 += part[256 * HD + (b * 4 + seg) * HD + f];
    }
    float mu = s * (1.0f / TT);
    float var = s2 * (1.0f / TT) - mu * mu;
    stats[b * HD + f] = mu;
    stats[BB * HD + b * HD + f] = rsqrtf(var + 1e-5f);
}

// ---------------------------------------------------------------------------
// Gate compute helper: 8 rows/thread, k-slice of 8, butterfly-reduced so
// lane q of each 8-lane group ends with row (r8+q)'s preactivation.
// ---------------------------------------------------------------------------
__device__ __forceinline__ float gate8(const float* __restrict__ wa,
                                       const float* __restrict__ wb,
                                       const float* __restrict__ srcA,
                                       const float* __restrict__ srcB,
                                       int q) {
    v2f sa[4], sb[4];
    const v2f* pa = (const v2f*)(srcA + 8 * q);
    const v2f* pb = (const v2f*)(srcB + 8 * q);
#pragma unroll
    for (int j = 0; j < 4; ++j) { sa[j] = pa[j]; sb[j] = pb[j]; }
    float v[8];
#pragma unroll
    for (int r = 0; r < 8; ++r) {
        v2f a;
        a.x = 0.f; a.y = 0.f;
#pragma unroll
        for (int j = 0; j < 4; ++j) {
            v2f wva, wvb;
            wva.x = wa[r * 8 + 2 * j]; wva.y = wa[r * 8 + 2 * j + 1];
            wvb.x = wb[r * 8 + 2 * j]; wvb.y = wb[r * 8 + 2 * j + 1];
            a = __builtin_elementwise_fma(wva, sa[j], a);
            a = __builtin_elementwise_fma(wvb, sb[j], a);
        }
        v[r] = a.x + a.y;
    }
    // butterfly multi-reduce: stage xor1 -> 4 vals, xor2 -> 2, xor4 -> 1
    const bool b0 = q & 1, b1 = q & 2, b2 = q & 4;
    float w0, w1, w2, w3;
    {
        float s0 = b0 ? v[0] : v[1], k0 = b0 ? v[1] : v[0];
        float s1 = b0 ? v[2] : v[3], k1 = b0 ? v[3] : v[2];
        float s2 = b0 ? v[4] : v[5], k2 = b0 ? v[5] : v[4];
        float s3 = b0 ? v[6] : v[7], k3 = b0 ? v[7] : v[6];
        w0 = k0 + __shfl_xor(s0, 1);
        w1 = k1 + __shfl_xor(s1, 1);
        w2 = k2 + __shfl_xor(s2, 1);
        w3 = k3 + __shfl_xor(s3, 1);
    }
    float y0, y1;
    {
        float s0 = b1 ? w0 : w1, k0 = b1 ? w1 : w0;
        float s1 = b1 ? w2 : w3, k1 = b1 ? w3 : w2;
        y0 = k0 + __shfl_xor(s0, 2);
        y1 = k1 + __shfl_xor(s1, 2);
    }
    float s0 = b2 ? y0 : y1, k0 = b2 ? y1 : y0;
    return k0 + __shfl_xor(s0, 4);
}

// ---------------------------------------------------------------------------
// Persistent recurrent kernel: 64 blocks x 512 threads, 2 barriers/step.
// Skewed: layer 0 runs one step ahead of layer 1. Weights pinned in VGPRs.
// ---------------------------------------------------------------------------
__global__ __launch_bounds__(512, 2) void rnn_fused(
    const float* __restrict__ x,
    const float* __restrict__ Wih0, const float* __restrict__ Whh0,
    const float* __restrict__ bih0, const float* __restrict__ bhh0,
    const float* __restrict__ Wih1, const float* __restrict__ Whh1,
    const float* __restrict__ bih1, const float* __restrict__ bhh1,
    const float* __restrict__ stats,
    float* __restrict__ h1out) {
    const int b = blockIdx.x;
    const int tid = threadIdx.x;
    const int q = tid & 7;          // k-slice [8q, 8q+8)
    const int rg = tid >> 3;        // rowgroup 0..63 (rows 8rg..8rg+8 of 512)
    const bool isL1 = rg < 32;      // rg<32: layer1 gates(t); else layer0 gates(t+1)
    const int r8 = (rg & 31) * 8;   // row base within the 256-row set
    const int gt = (tid >> 6) & 3;  // gate type 0:i 1:f 2:g 3:o (wave-uniform)

    // ---- per-thread weights: operand A is always h0; B is h1 (L1) or xn (L0)
    const float* Wa = isL1 ? Wih1 : Whh0;
    const float* Wb = isL1 ? Whh1 : Wih0;
    float wa[64], wb[64];
#pragma unroll
    for (int r = 0; r < 8; ++r) {
        const float4* pa = (const float4*)(Wa + (r8 + r) * HD + 8 * q);
        const float4* pb = (const float4*)(Wb + (r8 + r) * HD + 8 * q);
        float4 a0 = pa[0], a1 = pa[1];
        float4 c0v = pb[0], c1v = pb[1];
        wa[r * 8 + 0] = a0.x; wa[r * 8 + 1] = a0.y; wa[r * 8 + 2] = a0.z; wa[r * 8 + 3] = a0.w;
        wa[r * 8 + 4] = a1.x; wa[r * 8 + 5] = a1.y; wa[r * 8 + 6] = a1.z; wa[r * 8 + 7] = a1.w;
        wb[r * 8 + 0] = c0v.x; wb[r * 8 + 1] = c0v.y; wb[r * 8 + 2] = c0v.z; wb[r * 8 + 3] = c0v.w;
        wb[r * 8 + 4] = c1v.x; wb[r * 8 + 5] = c1v.y; wb[r * 8 + 6] = c1v.z; wb[r * 8 + 7] = c1v.w;
    }
    // pin: defeat load-sinking/remat so weights stay register-resident
#pragma unroll
    for (int i = 0; i < 64; ++i) {
        asm volatile("" : "+v"(wa[i]), "+v"(wb[i]));
    }

    const int myrow = r8 + q;  // row this thread finalizes after the butterfly
    const float Bsum = isL1 ? (bih1[myrow] + bhh1[myrow])
                            : (bih0[myrow] + bhh0[myrow]);
    const int feat = myrow & 63;
    const int uu_w = feat ^ ((feat >> 3) & 7);           // XOR-swizzled 16B unit
    const int gofs = (isL1 ? 0 : 256) + 4 * uu_w + gt;   // dword index in glds

    // staging constants: this thread stages features (4*tid)&63 .. +3
    const int fb = (4 * tid) & 63;
    const float4 mu4 = *(const float4*)&stats[b * HD + fb];
    const float4 rs4 = *(const float4*)&stats[BB * HD + b * HD + fb];

    __shared__ __align__(16) float h0_lds[HD];
    __shared__ __align__(16) float h1_lds[HD];
    __shared__ __align__(16) float glds[512];       // [L1: 4u+gt][L0: 256+4u+gt]
    __shared__ __align__(16) float xn[2][CH][HD];   // normalized x, chunk dbuf
    __shared__ __align__(16) float h1hist[CH][HD];  // h1 history for chunk flush

    const float* xrow = x + (size_t)b * TT * HD;
    float* hrow = h1out + (size_t)b * TT * HD;

    float c0 = 0.f, c1 = 0.f;

    // ---- prologue: zero state, stage chunk 0 ----
    if (tid < HD) { h0_lds[tid] = 0.f; h1_lds[tid] = 0.f; }
    {
        float4 xv = ((const float4*)xrow)[tid];  // steps 0..31
        float4 xnv;
        xnv.x = (xv.x - mu4.x) * rs4.x;
        xnv.y = (xv.y - mu4.y) * rs4.y;
        xnv.z = (xv.z - mu4.z) * rs4.z;
        xnv.w = (xv.w - mu4.w) * rs4.w;
        ((float4*)&xn[0][0][0])[tid] = xnv;
    }
    __syncthreads();
    // prologue gates (h0=h1=0, xn step 0); only the L0 half is used
    {
        const float* srcB = isL1 ? h1_lds : &xn[0][0][0];
        float gpre = gate8(wa, wb, h0_lds, srcB, q) + Bsum;
        float av = (gt == 2) ? tanhf_fast(gpre) : sigf(gpre);
        glds[gofs] = av;
    }
    __syncthreads();
    if (tid < HD) {  // update layer-0 only: c0(0), h0(0)
        const int f = tid;
        const int uu = f ^ ((f >> 3) & 7);
        float4 G0 = *(const float4*)&glds[256 + 4 * uu];
        c0 = G0.x * G0.z;  // c(-1)=0
        h0_lds[f] = G0.w * tanhf_fast(c0);
    }
    __syncthreads();

    float4 xs = make_float4(0.f, 0.f, 0.f, 0.f);
    for (int t = 0; t < TT; ++t) {
        const int tc = t & (CH - 1);

        // chunked input staging (amortizes barrier vmcnt drains over CH steps)
        if (tc == 0 && t + CH < TT) {
            xs = ((const float4*)(xrow + (size_t)(t + CH) * HD))[tid];
        }
        if (tc == CH / 2 && t + CH / 2 < TT) {
            const int pn = ((t >> 5) + 1) & 1;
            float4 xnv;
            xnv.x = (xs.x - mu4.x) * rs4.x;
            xnv.y = (xs.y - mu4.y) * rs4.y;
            xnv.z = (xs.z - mu4.z) * rs4.z;
            xnv.w = (xs.w - mu4.w) * rs4.w;
            ((float4*)&xn[pn][0][0])[tid] = xnv;
        }

        // ---- phase 1: gates1(t) on L1 waves, gates0(t+1) on L0 waves ----
        const int s1 = t + 1;
        const float* srcB = isL1 ? h1_lds : &xn[(s1 >> 5) & 1][s1 & (CH - 1)][0];
        float gpre = gate8(wa, wb, h0_lds, srcB, q) + Bsum;
        float av = (gt == 2) ? tanhf_fast(gpre) : sigf(gpre);
        glds[gofs] = av;
        __syncthreads();  // BAR A

        // ---- phase 2: both state updates (wave 0) ----
        if (tid < HD) {
            const int f = tid;
            const int uu = f ^ ((f >> 3) & 7);
            float4 G1 = *(const float4*)&glds[4 * uu];
            float4 G0 = *(const float4*)&glds[256 + 4 * uu];
            c1 = fmaf(G1.y, c1, G1.x * G1.z);
            float hv1 = G1.w * tanhf_fast(c1);
            h1_lds[f] = hv1;
            h1hist[tc][f] = hv1;
            c0 = fmaf(G0.y, c0, G0.x * G0.z);
            h0_lds[f] = G0.w * tanhf_fast(c0);
        }
        __syncthreads();  // BAR B

        // ---- flush h1 chunk to global (coalesced, once per CH steps) ----
        if (tc == CH - 1) {
            float4 hv = ((const float4*)&h1hist[0][0])[tid];
            ((float4*)(hrow + (size_t)(t - (CH - 1)) * HD))[tid] = hv;
        }
    }
}

// ---------------------------------------------------------------------------
// FC + bias + residual, in place on d_out (hout holds h1, rewritten as out).
// ---------------------------------------------------------------------------
__global__ __launch_bounds__(256) void fc_res(float* __restrict__ hout,
                                              const float* __restrict__ x,
                                              const float* __restrict__ Wfc,
                                              const float* __restrict__ bfc) {
    __shared__ __align__(16) float wfc_lds[HD * HD];
    __shared__ float bfc_lds[HD];
    const int tid = threadIdx.x;
#pragma unroll
    for (int i = 0; i < 4; ++i)
        ((float4*)wfc_lds)[tid + 256 * i] = ((const float4*)Wfc)[tid + 256 * i];
    if (tid < HD) bfc_lds[tid] = bfc[tid];

    const size_t row = (size_t)blockIdx.x * 256 + tid;
    float hr[HD];
    {
        const float4* hp = (const float4*)(hout + row * HD);
#pragma unroll
        for (int i = 0; i < 16; ++i) {
            float4 v = hp[i];
            hr[4 * i] = v.x; hr[4 * i + 1] = v.y;
            hr[4 * i + 2] = v.z; hr[4 * i + 3] = v.w;
        }
    }
    __syncthreads();

    const float4* xp = (const float4*)(x + row * HD);
    float4* op = (float4*)(hout + row * HD);
    for (int j4 = 0; j4 < 16; ++j4) {
        float s0 = 0.f, s1 = 0.f, s2 = 0.f, s3 = 0.f;
        const float* w0 = &wfc_lds[(4 * j4 + 0) * HD];
        const float* w1 = &wfc_lds[(4 * j4 + 1) * HD];
        const float* w2 = &wfc_lds[(4 * j4 + 2) * HD];
        const float* w3 = &wfc_lds[(4 * j4 + 3) * HD];
#pragma unroll
        for (int k = 0; k < HD; ++k) {
            s0 = fmaf(w0[k], hr[k], s0);
            s1 = fmaf(w1[k], hr[k], s1);
            s2 = fmaf(w2[k], hr[k], s2);
            s3 = fmaf(w3[k], hr[k], s3);
        }
        float4 xv = xp[j4];
        float4 o;
        o.x = s0 + bfc_lds[4 * j4 + 0] + xv.x;
        o.y = s1 + bfc_lds[4 * j4 + 1] + xv.y;
        o.z = s2 + bfc_lds[4 * j4 + 2] + xv.z;
        o.w = s3 + bfc_lds[4 * j4 + 3] + xv.w;
        op[j4] = o;
    }
}

// ---------------------------------------------------------------------------
extern "C" void kernel_launch(void* const* d_in, const int* in_sizes, int n_in,
                              void* d_out, int out_size, void* d_ws, size_t ws_size,
                              hipStream_t stream) {
    const float* x    = (const float*)d_in[0];
    const float* Wih0 = (const float*)d_in[1];
    const float* Whh0 = (const float*)d_in[2];
    const float* bih0 = (const float*)d_in[3];
    const float* bhh0 = (const float*)d_in[4];
    const float* Wih1 = (const float*)d_in[5];
    const float* Whh1 = (const float*)d_in[6];
    const float* bih1 = (const float*)d_in[7];
    const float* bhh1 = (const float*)d_in[8];
    const float* Wfc  = (const float*)d_in[9];
    const float* bfc  = (const float*)d_in[10];

    float* part  = (float*)d_ws;                 // 2*256*64 floats = 128 KiB
    float* stats = part + 2 * 256 * HD;          // 2*64*64 floats  =  32 KiB
    float* out   = (float*)d_out;

    stats_part<<<256, 256, 0, stream>>>(x, part);
    stats_fin<<<64, 64, 0, stream>>>(part, stats);
    rnn_fused<<<64, 512, 0, stream>>>(x, Wih0, Whh0, bih0, bhh0,
                                      Wih1, Whh1, bih1, bhh1, stats, out);
    fc_res<<<1024, 256, 0, stream>>>(out, x, Wfc, bfc);
}